// Round 6
// baseline (1157.710 us; speedup 1.0000x reference)
//
#include <hip/hip_runtime.h>

// ---------------- problem constants ----------------
constexpr int L  = 6;
constexpr int C  = 512;
constexpr int FC = 2048;
constexpr int H  = 8;
constexpr int KC = 64;
constexpr int T  = 1024;
constexpr int B  = 4;
#define SCALE 0.125f   // 1/sqrt(KC)
#define LOG2E 1.4426950408889634f

typedef __bf16 bf16_t;
typedef __bf16 bf16x8 __attribute__((ext_vector_type(8)));
typedef float  f32x4  __attribute__((ext_vector_type(4)));

// ---------------- workspace layout (bytes) ----------------
constexpr size_t OFF_XF    = 0;                               // f32 [B][T][C]      8 MB
constexpr size_t OFF_YF    = OFF_XF   + (size_t)B*T*C*4;      // f32 [B][T][C]      8 MB (partial 0)
constexpr size_t OFF_XPAD  = OFF_YF   + (size_t)B*T*C*4;      // bf16 [B][T+2][C]
constexpr size_t OFF_Q     = OFF_XPAD + (size_t)B*(T+2)*C*2;  // bf16 [B][T][C]  (alias: f32 partial 1 spans Q+K)
constexpr size_t OFF_K     = OFF_Q    + (size_t)B*T*C*2;
constexpr size_t OFF_VT    = OFF_K    + (size_t)B*T*C*2;      // bf16 [B][C][T]  (alias: f32 partial 2 spans VT+YA)
constexpr size_t OFF_YA    = OFF_VT   + (size_t)B*T*C*2;      // bf16 [B][T][C]
constexpr size_t OFF_MID   = OFF_YA   + (size_t)B*T*C*2;      // bf16 [B][T+2][FC]  16 MB
constexpr size_t OFF_WQKVO = OFF_MID  + (size_t)B*(T+2)*FC*2; // bf16 weight slots start here
// per-layer weight slot: [4][C][C] + [3][FC][C] + [3][C][FC] bf16
constexpr size_t WSLOT_ELEM = (size_t)4*C*C + (size_t)3*FC*C + (size_t)3*C*FC;   // 7,340,032
constexpr size_t WSLOT_BYTES = WSLOT_ELEM * 2;                                    // ~14.7 MB
constexpr size_t WS_HOISTED  = OFF_WQKVO + (size_t)L * WSLOT_BYTES;               // ~154 MB

// ---------------- async global->LDS (16B/lane) ----------------
__device__ __forceinline__ void gload_lds16(const bf16_t* g, bf16_t* l) {
    __builtin_amdgcn_global_load_lds((const __attribute__((address_space(1))) void*)g,
                                     (__attribute__((address_space(3))) void*)l, 16, 0, 0);
}

// ---------------- fused weight conversion (all three families, block-uniform ranges) ------
// layer = l0 + blockIdx.y; output slot = wbase + blockIdx.y * outStride (0 => shared slot).
__global__ __launch_bounds__(256) void cvt_all(const float* __restrict__ wq,
                                               const float* __restrict__ wk,
                                               const float* __restrict__ wv,
                                               const float* __restrict__ wo,
                                               const float* __restrict__ w1,
                                               const float* __restrict__ w2,
                                               bf16_t* __restrict__ wbase,
                                               int l0, size_t outStride) {
    const int l = l0 + blockIdx.y;
    bf16_t* out = wbase + (size_t)blockIdx.y * outStride;
    const float* a   = wq + (size_t)l * C * C;
    const float* bq_ = wk + (size_t)l * C * C;
    const float* c   = wv + (size_t)l * C * C;
    const float* d   = wo + (size_t)l * C * C;
    const float* w1l = w1 + (size_t)l * FC * C * 3;
    const float* w2l = w2 + (size_t)l * C * FC * 3;
    int i = blockIdx.x * 256 + threadIdx.x;
    constexpr int N4 = 4 * C * C;            // 1,048,576 (÷256)
    constexpr int NW1 = 3 * FC * C;          // 3,145,728 (÷256)
    if (i < N4) {
        int which = i >> 18;
        int idx   = i & ((1 << 18) - 1);
        const float* s = (which == 0) ? a : (which == 1) ? bq_ : (which == 2) ? c : d;
        out[i] = (bf16_t)s[idx];
    } else if (i < N4 + NW1) {
        int t = i - N4;                      // out [3][FC][C]
        int j = t >> 20;
        int rem = t & ((1 << 20) - 1);
        int fc = rem >> 9, cc = rem & 511;
        out[N4 + t] = (bf16_t)w1l[fc * (C * 3) + cc * 3 + j];
    } else {
        int t = i - N4 - NW1;                // out [3][C][FC]
        int j = t >> 20;
        int rem = t & ((1 << 20) - 1);
        int cc = rem >> 11, fc = rem & 2047;
        out[N4 + NW1 + t] = (bf16_t)w2l[cc * (FC * 3) + fc * 3 + j];
    }
}

// ---------------- transpose in/out ----------------
__global__ __launch_bounds__(256) void transpose_in(const float* __restrict__ x0,
                                                    float* __restrict__ xf,
                                                    bf16_t* __restrict__ xpad) {
    __shared__ float tile[32][33];
    int b = blockIdx.z, t0 = blockIdx.x * 32, c0 = blockIdx.y * 32;
    int tx = threadIdx.x, ty = threadIdx.y;
#pragma unroll
    for (int j = 0; j < 4; ++j)
        tile[ty + j * 8][tx] = x0[((size_t)b * C + c0 + ty + j * 8) * T + t0 + tx];
    __syncthreads();
#pragma unroll
    for (int j = 0; j < 4; ++j) {
        float v = tile[tx][ty + j * 8];
        long t = t0 + ty + j * 8;
        xf[((size_t)b * T + t) * C + c0 + tx] = v;
        xpad[((size_t)b * (T + 2) + t + 1) * C + c0 + tx] = (bf16_t)v;
    }
}

__global__ __launch_bounds__(256) void transpose_out(const float* __restrict__ xf,
                                                     float* __restrict__ out) {
    __shared__ float tile[32][33];
    int b = blockIdx.z, t0 = blockIdx.x * 32, c0 = blockIdx.y * 32;
    int tx = threadIdx.x, ty = threadIdx.y;
#pragma unroll
    for (int j = 0; j < 4; ++j)
        tile[ty + j * 8][tx] = xf[((size_t)b * T + t0 + ty + j * 8) * C + c0 + tx];
    __syncthreads();
#pragma unroll
    for (int j = 0; j < 4; ++j)
        out[((size_t)b * C + c0 + ty + j * 8) * T + t0 + tx] = tile[tx][ty + j * 8];
}

// ---------------- zero conv pads ----------------
__global__ __launch_bounds__(256) void zero_pads(bf16_t* __restrict__ xpad, bf16_t* __restrict__ midp) {
    int i = blockIdx.x * 256 + threadIdx.x;
    if (i < 4096) {
        int b = i >> 10, r = (i >> 9) & 1, c = i & 511;
        xpad[((size_t)b * (T + 2) + (size_t)r * (T + 1)) * C + c] = (bf16_t)0.f;
    } else {
        int j = i - 4096;
        int b = j >> 12, r = (j >> 11) & 1, c = j & 2047;
        midp[((size_t)b * (T + 2) + (size_t)r * (T + 1)) * FC + c] = (bf16_t)0.f;
    }
}

// ---------------- residual + NP-partial sum + layernorm (channel dim) ----------------
template <int NP>
__global__ __launch_bounds__(256) void add_ln(float* __restrict__ x,
                                              const float* __restrict__ p0, const float* __restrict__ p1,
                                              const float* __restrict__ p2,
                                              const float* __restrict__ g, const float* __restrict__ be,
                                              bf16_t* __restrict__ xpad) {
    long bt = blockIdx.x;
    int tid = threadIdx.x;
    float* xr = x + bt * C;
    float v0 = xr[tid] + p0[bt * C + tid] + p1[bt * C + tid];
    float v1 = xr[tid + 256] + p0[bt * C + tid + 256] + p1[bt * C + tid + 256];
    if (NP == 3) { v0 += p2[bt * C + tid]; v1 += p2[bt * C + tid + 256]; }
    float s = v0 + v1, q = v0 * v0 + v1 * v1;
#pragma unroll
    for (int m = 1; m < 64; m <<= 1) { s += __shfl_xor(s, m); q += __shfl_xor(q, m); }
    __shared__ float ss[4], qq[4];
    int wid = tid >> 6;
    if ((tid & 63) == 0) { ss[wid] = s; qq[wid] = q; }
    __syncthreads();
    s = ss[0] + ss[1] + ss[2] + ss[3];
    q = qq[0] + qq[1] + qq[2] + qq[3];
    float mean = s * (1.f / C);
    float var = q * (1.f / C) - mean * mean;
    float rstd = rsqrtf(var + 1e-4f);
    float o0 = (v0 - mean) * rstd * g[tid] + be[tid];
    float o1 = (v1 - mean) * rstd * g[tid + 256] + be[tid + 256];
    xr[tid] = o0; xr[tid + 256] = o1;
    long b = bt >> 10, t = bt & (T - 1);
    bf16_t* xp = xpad + (b * (T + 2) + t + 1) * C;
    xp[tid] = (bf16_t)o0; xp[tid + 256] = (bf16_t)o1;
}

// ---------------- 128xBNT GEMM, BK=64, global_load_lds + XOR-swizzled LDS ----------------
// BNT=128: 4 waves in 2x2, acc[4][4].  BNT=64: 4 waves in 4x1 (32 M-rows each), acc[2][4].
// BNT=64 grids land on multiples of 256 blocks -> balanced CU load.
template <int OUTMODE, bool RELU, int NSPLIT, int IPT, int NTAPS, int BNT>
__global__ __launch_bounds__(256) void gemm128(
    const bf16_t* __restrict__ A, long batchStrideA, int lda,
    const bf16_t* __restrict__ Bw, long tapStrideB, int ldb,
    const float* __restrict__ bias0, const float* __restrict__ bias1,
    const float* __restrict__ bias2,
    void* __restrict__ Dp, void* __restrict__ D1p, void* __restrict__ D2p,
    long batchStrideD, int ldd) {
    __shared__ bf16_t As[128 * 64];
    __shared__ bf16_t Bs[BNT * 64];
    constexpr int WAVES_Y = (BNT == 128) ? 2 : 4;
    constexpr int WM = 128 / WAVES_Y;       // M-rows per wave: 64 or 32
    constexpr int MT = WM / 16;             // 4 or 2
    constexpr int CPW = BNT / 32;           // B chunks per wave: 4 or 2
    const int tid = threadIdx.x;
    const int lane = tid & 63, wid = tid >> 6;
    const int l15 = lane & 15, quad = lane >> 4;
    const int wy = (BNT == 128) ? (wid >> 1) : wid;
    const int wx = (BNT == 128) ? (wid & 1) : 0;
    const int nb = gridDim.z / NSPLIT;
    const int split = (NSPLIT > 1) ? ((int)blockIdx.z / nb) : 0;
    const int b = (int)blockIdx.z - split * nb;

    const bf16_t* Ab = A + (long)b * batchStrideA + (long)blockIdx.y * 128 * lda;
    const bf16_t* Bb = Bw + (long)blockIdx.x * BNT * ldb;

    const int lrow = lane >> 3;
    const int lcolsw = ((lane & 7) ^ lrow) * 8;

    f32x4 acc[MT][4];
#pragma unroll
    for (int i = 0; i < MT; ++i)
#pragma unroll
        for (int j = 0; j < 4; ++j) acc[i][j] = (f32x4){0.f, 0.f, 0.f, 0.f};

    constexpr int itersAll = IPT * NTAPS;
    constexpr int per = itersAll / NSPLIT;
    const int it0 = split * per;

    for (int it = it0; it < it0 + per; ++it) {
        const int tap = (NTAPS == 1) ? 0 : (it / IPT);
        const int k0 = (it - tap * IPT) * 64;
        const bf16_t* At = Ab + (long)tap * lda + k0;
        const bf16_t* Bt = Bb + (long)tap * tapStrideB + k0;
        __syncthreads();
#pragma unroll
        for (int i = 0; i < 4; ++i) {           // A: 16 chunks of 8 rows
            int chunk = wid * 4 + i;
            int row = chunk * 8 + lrow;
            gload_lds16(At + (long)row * lda + lcolsw, As + chunk * 512 + lane * 8);
        }
#pragma unroll
        for (int i = 0; i < CPW; ++i) {         // B: BNT/8 chunks
            int chunk = wid * CPW + i;
            int row = chunk * 8 + lrow;
            gload_lds16(Bt + (long)row * ldb + lcolsw, Bs + chunk * 512 + lane * 8);
        }
        __syncthreads();
#pragma unroll
        for (int ks = 0; ks < 2; ++ks) {
            bf16x8 bfr[4], afr[MT];
#pragma unroll
            for (int nt = 0; nt < 4; ++nt) {
                int row = wx * 64 + nt * 16 + l15;
                bfr[nt] = *(const bf16x8*)&Bs[row * 64 + (((ks * 4 + quad) ^ (l15 & 7)) * 8)];
            }
#pragma unroll
            for (int mt = 0; mt < MT; ++mt) {
                int row = wy * WM + mt * 16 + l15;
                afr[mt] = *(const bf16x8*)&As[row * 64 + (((ks * 4 + quad) ^ (l15 & 7)) * 8)];
            }
#pragma unroll
            for (int mt = 0; mt < MT; ++mt)
#pragma unroll
                for (int nt = 0; nt < 4; ++nt)
                    acc[mt][nt] = __builtin_amdgcn_mfma_f32_16x16x32_bf16(afr[mt], bfr[nt], acc[mt][nt], 0, 0, 0);
        }
    }

    const long m0 = (long)blockIdx.y * 128 + wy * WM;
    const int n0g = (int)blockIdx.x * BNT + wx * 64;
#pragma unroll
    for (int mt = 0; mt < MT; ++mt) {
        long rowb = m0 + mt * 16 + quad * 4;
#pragma unroll
        for (int nt = 0; nt < 4; ++nt) {
            int col = n0g + nt * 16 + l15;
            if (OUTMODE == 0) {
                float bb = (split == 0) ? bias0[col] : 0.f;
                float* D = ((split == 0) ? (float*)Dp : (split == 1) ? (float*)D1p : (float*)D2p)
                           + (long)b * batchStrideD;
#pragma unroll
                for (int r = 0; r < 4; ++r) D[(rowb + r) * ldd + col] = acc[mt][nt][r] + bb;
            } else if (OUTMODE == 1) {
                float bb = bias0[col];
                bf16_t* D = (bf16_t*)Dp + (long)b * batchStrideD;
#pragma unroll
                for (int r = 0; r < 4; ++r) {
                    float v = acc[mt][nt][r] + bb;
                    if (RELU) v = fmaxf(v, 0.f);
                    D[(rowb + r) * ldd + col] = (bf16_t)v;
                }
            } else {  // QKV fused
                int which = col >> 9, cl = col & 511;
                const float* bp = (which == 0) ? bias0 : (which == 1) ? bias1 : bias2;
                float bb = bp[cl];
                if (which < 2) {
                    bf16_t* D = (bf16_t*)((which == 0) ? Dp : D1p) + (long)b * T * C;
#pragma unroll
                    for (int r = 0; r < 4; ++r) D[(rowb + r) * C + cl] = (bf16_t)(acc[mt][nt][r] + bb);
                } else {
                    bf16_t* D = (bf16_t*)D2p + (long)b * C * T;
                    union { bf16_t h[4]; uint2 u; } pk;
#pragma unroll
                    for (int r = 0; r < 4; ++r) pk.h[r] = (bf16_t)(acc[mt][nt][r] + bb);
                    *(uint2*)(D + (long)cl * T + rowb) = pk.u;
                }
            }
        }
    }
}

// ---------------- fused attention: swapped-operand (S^T / O^T) flash kernel ----------------
// grid (T/64, H, B), 256 thr. Wave owns Q rows wid*16..+15. S^T = mfma(K,Q): lane holds 16
// scores of ONE Q row -> softmax = register tree + 2 shfls; O^T = mfma(V,P).
// ONE barrier per KV iteration: K(st+1), V(st+1) both staged one-ahead into the opposite
// dbuf slot; the barrier at the top of iter st+1 drains them (vmcnt(0) at s_barrier).
// NOTE: no second barrier — it would force-drain the in-flight prefetch mid-iteration
// (the m97 barrier-drain stall). P strips are wave-private, so no barrier is needed there.
__global__ __launch_bounds__(256) void attn_kernel(const bf16_t* __restrict__ q,
                                                   const bf16_t* __restrict__ k,
                                                   const bf16_t* __restrict__ vT,
                                                   const float* __restrict__ relk,
                                                   bf16_t* __restrict__ y) {
    const int b = blockIdx.z, h = blockIdx.y;
    const int qt0 = blockIdx.x * 64;
    __shared__ bf16_t qps[64 * 72];      // swizzled Q [64][64] first, then P strips [8w][16][72]
    __shared__ bf16_t ktb[2][64 * 64];   // double-buffered swizzled K tiles
    __shared__ bf16_t vtb[2][64 * 64];   // double-buffered swizzled V^T tiles
    __shared__ float  rl[64][12];        // rel logits (exp2 domain)

    const int tid = threadIdx.x;
    const int lane = tid & 63, wid = tid >> 6;
    const int l15 = lane & 15, quad = lane >> 4;
    const int lrow = lane >> 3;                // 0..7 row within 8-row chunk
    const int su   = ((lane & 7) ^ lrow) * 8;  // swizzled source elem offset

    const bf16_t* qbase = q + ((size_t)(b * T + qt0)) * C + h * 64;
    const bf16_t* kbs = k + ((size_t)(b * T)) * C + h * 64;
    const bf16_t* vbs = vT + ((size_t)(b * C + h * 64)) * T;

    // prologue: stage Q + K/V tile 0, all async
#pragma unroll
    for (int i = 0; i < 2; ++i) {
        int chunk = wid * 2 + i;
        int row = chunk * 8 + lrow;
        gload_lds16(qbase + (long)row * C + su, qps + chunk * 512 + lane * 8);
        gload_lds16(kbs + (long)row * C + su, ktb[0] + chunk * 512 + lane * 8);
        gload_lds16(vbs + (long)row * T + su, vtb[0] + chunk * 512 + lane * 8);
    }
    __syncthreads();

    // rel logits: rl[r][j] = (SCALE*LOG2E) * q[r]·relk[j]   (reads swizzled qps)
    for (int i = tid; i < 64 * 9; i += 256) {
        int r = i / 9, j = i - r * 9;
        float acc = 0.f;
#pragma unroll
        for (int d = 0; d < 64; ++d)
            acc += (float)qps[r * 64 + ((d >> 3) ^ (r & 7)) * 8 + (d & 7)] * relk[j * 64 + d];
        rl[r][j] = acc * (SCALE * LOG2E);
    }
    __syncthreads();   // rl visible; all waves done reading qps as Q (P strips may overwrite)

    // Q fragments (B-operand role: col = q = l15 of wave's 16-row strip)
    const int qrow = wid * 16 + l15;
    bf16x8 af[2];
#pragma unroll
    for (int ks = 0; ks < 2; ++ks)
        af[ks] = *(const bf16x8*)&qps[qrow * 64 + (((ks * 4 + quad) ^ (qrow & 7)) * 8)];
    const float rl0 = rl[qrow][0], rl8 = rl[qrow][8];   // uniform-tile biases (register)

    float m_i = -1e30f, l_i = 0.f;   // lane-scalar online-softmax state (q = qrow)
    f32x4 o[4];
#pragma unroll
    for (int dn = 0; dn < 4; ++dn) o[dn] = (f32x4){0.f, 0.f, 0.f, 0.f};

    bf16_t* myP = qps + wid * (16 * 72);

    for (int st = 0; st < T / 64; ++st) {
        // single barrier: stage(st) complete (vmcnt drain), all waves done with buf[(st+1)&1]
        __syncthreads();
        if (st < T / 64 - 1) {
            const bf16_t* kb2 = kbs + (size_t)(st + 1) * 64 * C;
            const bf16_t* vb2 = vbs + (st + 1) * 64;
            bf16_t* kd = ktb[(st + 1) & 1];
            bf16_t* vd = vtb[(st + 1) & 1];
#pragma unroll
            for (int i = 0; i < 2; ++i) {
                int chunk = wid * 2 + i, row = chunk * 8 + lrow;
                gload_lds16(kb2 + (long)row * C + su, kd + chunk * 512 + lane * 8);
                gload_lds16(vb2 + (long)row * T + su, vd + chunk * 512 + lane * 8);
            }
        }
        const bf16_t* ktc = ktb[st & 1];
        const bf16_t* vtc = vtb[st & 1];

        // S^T tile: sc[nt][r] = S[s = nt*16 + quad*4 + r][q = l15]  (A=K, B=Q)
        f32x4 sc[4];
#pragma unroll
        for (int nt = 0; nt < 4; ++nt) {
            f32x4 a = (f32x4){0.f, 0.f, 0.f, 0.f};
#pragma unroll
            for (int ks = 0; ks < 2; ++ks) {
                int rr = nt * 16 + l15;
                bf16x8 kfr = *(const bf16x8*)&ktc[rr * 64 + (((ks * 4 + quad) ^ (l15 & 7)) * 8)];
                a = __builtin_amdgcn_mfma_f32_16x16x32_bf16(kfr, af[ks], a, 0, 0, 0);
            }
            sc[nt] = a;
        }

        // scale (exp2 domain) + rel bias.  d = s_g - q_g; j = clamp(d+4, 0, 8).
        const int base = st * 64 - qt0 - wid * 16;
        if (base >= 32) {
#pragma unroll
            for (int nt = 0; nt < 4; ++nt)
#pragma unroll
                for (int r = 0; r < 4; ++r) sc[nt][r] = sc[nt][r] * (SCALE * LOG2E) + rl8;
        } else if (base <= -80) {
#pragma unroll
            for (int nt = 0; nt < 4; ++nt)
#pragma unroll
                for (int r = 0; r < 4; ++r) sc[nt][r] = sc[nt][r] * (SCALE * LOG2E) + rl0;
        } else {
#pragma unroll
            for (int nt = 0; nt < 4; ++nt)
#pragma unroll
                for (int r = 0; r < 4; ++r) {
                    int j = base + nt * 16 + quad * 4 + r - l15 + 4;
                    j = j < 0 ? 0 : (j > 8 ? 8 : j);
                    sc[nt][r] = sc[nt][r] * (SCALE * LOG2E) + rl[qrow][j];
                }
        }

        // online softmax (base 2): 16 values in-lane + cross-quad combine (xor16, xor32)
        float mx = fmaxf(fmaxf(fmaxf(sc[0][0], sc[0][1]), fmaxf(sc[0][2], sc[0][3])),
                         fmaxf(fmaxf(sc[1][0], sc[1][1]), fmaxf(sc[1][2], sc[1][3])));
        mx = fmaxf(mx, fmaxf(fmaxf(fmaxf(sc[2][0], sc[2][1]), fmaxf(sc[2][2], sc[2][3])),
                             fmaxf(fmaxf(sc[3][0], sc[3][1]), fmaxf(sc[3][2], sc[3][3]))));
        mx = fmaxf(mx, __shfl_xor(mx, 16));
        mx = fmaxf(mx, __shfl_xor(mx, 32));
        float mn = fmaxf(m_i, mx);
        float alpha = exp2f(m_i - mn);
        m_i = mn;
        float rs = 0.f;
#pragma unroll
        for (int nt = 0; nt < 4; ++nt)
#pragma unroll
            for (int r = 0; r < 4; ++r) {
                float p = exp2f(sc[nt][r] - m_i);
                sc[nt][r] = p;
                rs += p;
            }
        rs += __shfl_xor(rs, 16);
        rs += __shfl_xor(rs, 32);
        l_i = l_i * alpha + rs;
#pragma unroll
        for (int dn = 0; dn < 4; ++dn) o[dn] *= alpha;

        // P strip: myP[q=l15][s] — wave-private, packed 4 x ds_write_b64 (no barrier needed)
#pragma unroll
        for (int nt = 0; nt < 4; ++nt) {
            union { bf16_t hh[4]; uint2 u; } pk;
#pragma unroll
            for (int r = 0; r < 4; ++r) pk.hh[r] = (bf16_t)sc[nt][r];
            *(uint2*)&myP[l15 * 72 + nt * 16 + quad * 4] = pk.u;
        }

        // O^T: o[dn] += mfma(A = V^T rows d, B = P^T cols q)  -> row = d, col = q = l15
        bf16x8 pb[2];
#pragma unroll
        for (int ks = 0; ks < 2; ++ks)
            pb[ks] = *(const bf16x8*)&myP[l15 * 72 + ks * 32 + quad * 8];
#pragma unroll
        for (int dn = 0; dn < 4; ++dn)
#pragma unroll
            for (int ks = 0; ks < 2; ++ks) {
                int rr = dn * 16 + l15;
                bf16x8 vf = *(const bf16x8*)&vtc[rr * 64 + (((ks * 4 + quad) ^ (l15 & 7)) * 8)];
                o[dn] = __builtin_amdgcn_mfma_f32_16x16x32_bf16(vf, pb[ks], o[dn], 0, 0, 0);
            }
    }

    // epilogue: lane (l15, quad) holds O^T[d = dn*16 + quad*4 + r][q = qrow]; write 8B packs
    float linv = 1.f / l_i;
    bf16_t* yb = y + ((size_t)(b * T + qt0 + qrow)) * C + h * 64;
#pragma unroll
    for (int dn = 0; dn < 4; ++dn) {
        union { bf16_t hh[4]; uint2 u; } pk;
#pragma unroll
        for (int r = 0; r < 4; ++r) pk.hh[r] = (bf16_t)(o[dn][r] * linv);
        *(uint2*)(yb + dn * 16 + quad * 4) = pk.u;
    }
}

// ---------------- host launch ----------------
extern "C" void kernel_launch(void* const* d_in, const int* in_sizes, int n_in,
                              void* d_out, int out_size, void* d_ws, size_t ws_size,
                              hipStream_t stream) {
    const float* x0  = (const float*)d_in[0];
    const float* wq  = (const float*)d_in[1];
    const float* bq  = (const float*)d_in[2];
    const float* wk  = (const float*)d_in[3];
    const float* bk  = (const float*)d_in[4];
    const float* wv  = (const float*)d_in[5];
    const float* bv  = (const float*)d_in[6];
    const float* wo  = (const float*)d_in[7];
    const float* bo  = (const float*)d_in[8];
    const float* rlk = (const float*)d_in[9];
    const float* g1  = (const float*)d_in[10];
    const float* be1 = (const float*)d_in[11];
    const float* w1  = (const float*)d_in[12];
    const float* bb1 = (const float*)d_in[13];
    const float* w2  = (const float*)d_in[14];
    const float* bb2 = (const float*)d_in[15];
    const float* g2  = (const float*)d_in[16];
    const float* be2 = (const float*)d_in[17];

    char* ws = (char*)d_ws;
    float*  xf    = (float*)(ws + OFF_XF);
    float*  yf    = (float*)(ws + OFF_YF);
    float*  yf2   = (float*)(ws + OFF_Q);       // aliases Q+K (dead at use time)
    float*  yf3   = (float*)(ws + OFF_VT);      // aliases VT+YA (dead during FFN2)
    bf16_t* xpad  = (bf16_t*)(ws + OFF_XPAD);
    bf16_t* qb    = (bf16_t*)(ws + OFF_Q);
    bf16_t* kb    = (bf16_t*)(ws + OFF_K);
    bf16_t* vTb   = (bf16_t*)(ws + OFF_VT);
    bf16_t* yab   = (bf16_t*)(ws + OFF_YA);
    bf16_t* midp  = (bf16_t*)(ws + OFF_MID);
    bf16_t* wslot0 = (bf16_t*)(ws + OFF_WQKVO);

    const bool hoist = ws_size >= WS_HOISTED;   // fills suggest ws ~302 MB; guarded anyway

    transpose_in<<<dim3(T / 32, C / 32, B), dim3(32, 8), 0, stream>>>(x0, xf, xpad);
    zero_pads<<<80, 256, 0, stream>>>(xpad, midp);

    constexpr int CVT_BLOCKS = (int)(WSLOT_ELEM / 256);

    if (hoist)   // convert all 6 layers' weights once, before the layer loop
        cvt_all<<<dim3(CVT_BLOCKS, L), 256, 0, stream>>>(wq, wk, wv, wo, w1, w2,
                                                         wslot0, 0, WSLOT_ELEM);

    for (int l = 0; l < L; ++l) {
        if (!hoist)
            cvt_all<<<dim3(CVT_BLOCKS, 1), 256, 0, stream>>>(wq, wk, wv, wo, w1, w2,
                                                             wslot0, l, 0);
        bf16_t* wbase = wslot0 + (hoist ? (size_t)l * WSLOT_ELEM : 0);
        bf16_t* wqkvo = wbase;
        bf16_t* w1b   = wbase + (size_t)4 * C * C;
        bf16_t* w2b   = wbase + (size_t)4 * C * C + (size_t)3 * FC * C;

        // fused QKV projection: N=1536, K=512 -> qb, kb, vT   (BN=64: 768 blocks = 3/CU)
        gemm128<3, false, 1, 8, 1, 64><<<dim3(1536 / 64, T / 128, B), 256, 0, stream>>>(
            xpad + C, (long)(T + 2) * C, C, wqkvo, 0, C,
            bq + l * C, bk + l * C, bv + l * C,
            (void*)qb, (void*)kb, (void*)vTb, 0, 0);

        attn_kernel<<<dim3(T / 64, H, B), 256, 0, stream>>>(qb, kb, vTb, rlk + (size_t)l * 9 * KC, yab);

        // O projection, split-K x2 -> f32 partials yf, yf2   (BN=64: 512 blocks = 2/CU)
        gemm128<0, false, 2, 8, 1, 64><<<dim3(C / 64, T / 128, 2 * B), 256, 0, stream>>>(
            yab, (long)T * C, C, wqkvo + 3 * C * C, 0, C,
            bo + l * C, nullptr, nullptr,
            (void*)yf, (void*)yf2, nullptr, (long)T * C, C);

        add_ln<2><<<B * T, 256, 0, stream>>>(xf, yf, yf2, nullptr, g1 + l * C, be1 + l * C, xpad);

        // FFN1: conv K=3 + bias + relu -> bf16 mid_pad rows 1..T   (BN=128: 512 blocks, balanced)
        gemm128<1, true, 1, 8, 3, 128><<<dim3(FC / 128, T / 128, B), 256, 0, stream>>>(
            xpad, (long)(T + 2) * C, C, w1b, (long)FC * C, C,
            bb1 + l * FC, nullptr, nullptr,
            (void*)(midp + FC), nullptr, nullptr, (long)(T + 2) * FC, FC);

        // FFN2: conv K=3, split-K x3 (tap-aligned) -> f32 partials   (BN=64: 768 blocks = 3/CU)
        gemm128<0, false, 3, 32, 3, 64><<<dim3(C / 64, T / 128, 3 * B), 256, 0, stream>>>(
            midp, (long)(T + 2) * FC, FC, w2b, (long)C * FC, FC,
            bb2 + l * C, nullptr, nullptr,
            (void*)yf, (void*)yf2, (void*)yf3, (long)T * C, C);

        add_ln<3><<<B * T, 256, 0, stream>>>(xf, yf, yf2, yf3, g2 + l * C, be2 + l * C, xpad);
    }

    transpose_out<<<dim3(T / 32, C / 32, B), dim3(32, 8), 0, stream>>>(xf, (float*)d_out);
}

// Round 7
// 1150.653 us; speedup vs baseline: 1.0061x; 1.0061x over previous
//
#include <hip/hip_runtime.h>

// ---------------- problem constants ----------------
constexpr int L  = 6;
constexpr int C  = 512;
constexpr int FC = 2048;
constexpr int H  = 8;
constexpr int KC = 64;
constexpr int T  = 1024;
constexpr int B  = 4;
#define SCALE 0.125f   // 1/sqrt(KC)
#define LOG2E 1.4426950408889634f

typedef __bf16 bf16_t;
typedef __bf16 bf16x8 __attribute__((ext_vector_type(8)));
typedef float  f32x4  __attribute__((ext_vector_type(4)));

// ---------------- workspace layout (bytes) ----------------
constexpr size_t OFF_XF    = 0;                               // f32 [B][T][C]      8 MB
constexpr size_t OFF_YF    = OFF_XF   + (size_t)B*T*C*4;      // f32 [B][T][C]      8 MB (partial 0)
constexpr size_t OFF_XPAD  = OFF_YF   + (size_t)B*T*C*4;      // bf16 [B][T+2][C]
constexpr size_t OFF_Q     = OFF_XPAD + (size_t)B*(T+2)*C*2;  // bf16 [B][T][C]  (alias: f32 partial 1 spans Q+K)
constexpr size_t OFF_K     = OFF_Q    + (size_t)B*T*C*2;
constexpr size_t OFF_VT    = OFF_K    + (size_t)B*T*C*2;      // bf16 [B][C][T]  (alias: f32 partial 2 spans VT+YA)
constexpr size_t OFF_YA    = OFF_VT   + (size_t)B*T*C*2;      // bf16 [B][T][C]
constexpr size_t OFF_MID   = OFF_YA   + (size_t)B*T*C*2;      // bf16 [B][T+2][FC]  16 MB
constexpr size_t OFF_WQKVO = OFF_MID  + (size_t)B*(T+2)*FC*2; // bf16 weight slots start here
// per-layer weight slot: [4][C][C] + [3][FC][C] + [3][C][FC] bf16
constexpr size_t WSLOT_ELEM = (size_t)4*C*C + (size_t)3*FC*C + (size_t)3*C*FC;   // 7,340,032
constexpr size_t WSLOT_BYTES = WSLOT_ELEM * 2;                                    // ~14.7 MB
constexpr size_t WS_HOISTED  = OFF_WQKVO + (size_t)L * WSLOT_BYTES;               // ~154 MB

// ---------------- async global->LDS (16B/lane) ----------------
__device__ __forceinline__ void gload_lds16(const bf16_t* g, bf16_t* l) {
    __builtin_amdgcn_global_load_lds((const __attribute__((address_space(1))) void*)g,
                                     (__attribute__((address_space(3))) void*)l, 16, 0, 0);
}

// ---------------- fused weight conversion — fully coalesced/vectorized ----------------
// Part 1 (512 blk):  [4][C][C] f32 -> bf16 linear copy, 8 elem/thread (2x float4 -> 16B store).
// Part 2 (1024 blk): w1 [FC][C][3] -> [3][FC][C]; thread owns 4 consecutive (fc,cc) triples:
//                    3x float4 contiguous read (48B), 3x uint2 (8B) contiguous plane writes.
// Part 3 (1024 blk): w2 [C][FC][3] -> [3][C][FC]; same structure, t = cc*FC + fc.
// layer = l0 + blockIdx.y; output slot = wbase + blockIdx.y * outStride (0 => shared slot).
__global__ __launch_bounds__(256) void cvt_all(const float* __restrict__ wq,
                                               const float* __restrict__ wk,
                                               const float* __restrict__ wv,
                                               const float* __restrict__ wo,
                                               const float* __restrict__ w1,
                                               const float* __restrict__ w2,
                                               bf16_t* __restrict__ wbase,
                                               int l0, size_t outStride) {
    const int l = l0 + blockIdx.y;
    bf16_t* out = wbase + (size_t)blockIdx.y * outStride;
    constexpr int N4  = 4 * C * C;           // 1,048,576
    constexpr int NW1 = 3 * FC * C;          // 3,145,728
    constexpr int P1B = N4 / (256 * 8);      // 512 blocks
    constexpr int P2B = (FC * C / 4) / 256;  // 1024 blocks
    const int blk = blockIdx.x, tid = threadIdx.x;

    if (blk < P1B) {                          // ---- QKV/O copy, 8 elems/thread
        int idx8 = (blk * 256 + tid) * 8;
        int which = idx8 >> 18;               // C*C = 2^18
        int off   = idx8 & ((1 << 18) - 1);
        const float* src = ((which == 0) ? wq : (which == 1) ? wk : (which == 2) ? wv : wo)
                           + (size_t)l * C * C + off;
        float4 a = *(const float4*)src;
        float4 b = *(const float4*)(src + 4);
        union { bf16_t h[8]; uint4 u; } pk;
        pk.h[0] = (bf16_t)a.x; pk.h[1] = (bf16_t)a.y; pk.h[2] = (bf16_t)a.z; pk.h[3] = (bf16_t)a.w;
        pk.h[4] = (bf16_t)b.x; pk.h[5] = (bf16_t)b.y; pk.h[6] = (bf16_t)b.z; pk.h[7] = (bf16_t)b.w;
        *(uint4*)(out + idx8) = pk.u;
    } else if (blk < P1B + P2B) {             // ---- w1 transpose
        int t = ((blk - P1B) * 256 + tid);    // t in [0, FC*C/4): 4 triples
        const float* s = w1 + (size_t)l * FC * C * 3 + (size_t)t * 12;
        float4 a = *(const float4*)s;
        float4 b = *(const float4*)(s + 4);
        float4 c = *(const float4*)(s + 8);
        union { bf16_t h[4]; uint2 u; } p0, p1, p2;
        p0.h[0] = (bf16_t)a.x; p0.h[1] = (bf16_t)a.w; p0.h[2] = (bf16_t)b.z; p0.h[3] = (bf16_t)c.y;
        p1.h[0] = (bf16_t)a.y; p1.h[1] = (bf16_t)b.x; p1.h[2] = (bf16_t)b.w; p1.h[3] = (bf16_t)c.z;
        p2.h[0] = (bf16_t)a.z; p2.h[1] = (bf16_t)b.y; p2.h[2] = (bf16_t)c.x; p2.h[3] = (bf16_t)c.w;
        bf16_t* o0 = out + N4;
        ((uint2*)(o0))[t]              = p0.u;
        ((uint2*)(o0 + FC * C))[t]     = p1.u;
        ((uint2*)(o0 + 2 * FC * C))[t] = p2.u;
    } else {                                  // ---- w2 transpose
        int t = ((blk - P1B - P2B) * 256 + tid);  // t in [0, C*FC/4)
        const float* s = w2 + (size_t)l * C * FC * 3 + (size_t)t * 12;
        float4 a = *(const float4*)s;
        float4 b = *(const float4*)(s + 4);
        float4 c = *(const float4*)(s + 8);
        union { bf16_t h[4]; uint2 u; } p0, p1, p2;
        p0.h[0] = (bf16_t)a.x; p0.h[1] = (bf16_t)a.w; p0.h[2] = (bf16_t)b.z; p0.h[3] = (bf16_t)c.y;
        p1.h[0] = (bf16_t)a.y; p1.h[1] = (bf16_t)b.x; p1.h[2] = (bf16_t)b.w; p1.h[3] = (bf16_t)c.z;
        p2.h[0] = (bf16_t)a.z; p2.h[1] = (bf16_t)b.y; p2.h[2] = (bf16_t)c.x; p2.h[3] = (bf16_t)c.w;
        bf16_t* o0 = out + N4 + NW1;
        ((uint2*)(o0))[t]             = p0.u;
        ((uint2*)(o0 + C * FC))[t]    = p1.u;
        ((uint2*)(o0 + 2 * C * FC))[t] = p2.u;
    }
}
constexpr int CVT_BLOCKS = (4 * C * C) / (256 * 8) + 2 * ((FC * C / 4) / 256);   // 2560

// ---------------- transpose in/out ----------------
__global__ __launch_bounds__(256) void transpose_in(const float* __restrict__ x0,
                                                    float* __restrict__ xf,
                                                    bf16_t* __restrict__ xpad) {
    __shared__ float tile[32][33];
    int b = blockIdx.z, t0 = blockIdx.x * 32, c0 = blockIdx.y * 32;
    int tx = threadIdx.x, ty = threadIdx.y;
#pragma unroll
    for (int j = 0; j < 4; ++j)
        tile[ty + j * 8][tx] = x0[((size_t)b * C + c0 + ty + j * 8) * T + t0 + tx];
    __syncthreads();
#pragma unroll
    for (int j = 0; j < 4; ++j) {
        float v = tile[tx][ty + j * 8];
        long t = t0 + ty + j * 8;
        xf[((size_t)b * T + t) * C + c0 + tx] = v;
        xpad[((size_t)b * (T + 2) + t + 1) * C + c0 + tx] = (bf16_t)v;
    }
}

__global__ __launch_bounds__(256) void transpose_out(const float* __restrict__ xf,
                                                     float* __restrict__ out) {
    __shared__ float tile[32][33];
    int b = blockIdx.z, t0 = blockIdx.x * 32, c0 = blockIdx.y * 32;
    int tx = threadIdx.x, ty = threadIdx.y;
#pragma unroll
    for (int j = 0; j < 4; ++j)
        tile[ty + j * 8][tx] = xf[((size_t)b * T + t0 + ty + j * 8) * C + c0 + tx];
    __syncthreads();
#pragma unroll
    for (int j = 0; j < 4; ++j)
        out[((size_t)b * C + c0 + ty + j * 8) * T + t0 + tx] = tile[tx][ty + j * 8];
}

// ---------------- zero conv pads ----------------
__global__ __launch_bounds__(256) void zero_pads(bf16_t* __restrict__ xpad, bf16_t* __restrict__ midp) {
    int i = blockIdx.x * 256 + threadIdx.x;
    if (i < 4096) {
        int b = i >> 10, r = (i >> 9) & 1, c = i & 511;
        xpad[((size_t)b * (T + 2) + (size_t)r * (T + 1)) * C + c] = (bf16_t)0.f;
    } else {
        int j = i - 4096;
        int b = j >> 12, r = (j >> 11) & 1, c = j & 2047;
        midp[((size_t)b * (T + 2) + (size_t)r * (T + 1)) * FC + c] = (bf16_t)0.f;
    }
}

// ---------------- residual + NP-partial sum + layernorm (channel dim) ----------------
template <int NP>
__global__ __launch_bounds__(256) void add_ln(float* __restrict__ x,
                                              const float* __restrict__ p0, const float* __restrict__ p1,
                                              const float* __restrict__ p2,
                                              const float* __restrict__ g, const float* __restrict__ be,
                                              bf16_t* __restrict__ xpad) {
    long bt = blockIdx.x;
    int tid = threadIdx.x;
    float* xr = x + bt * C;
    float v0 = xr[tid] + p0[bt * C + tid] + p1[bt * C + tid];
    float v1 = xr[tid + 256] + p0[bt * C + tid + 256] + p1[bt * C + tid + 256];
    if (NP == 3) { v0 += p2[bt * C + tid]; v1 += p2[bt * C + tid + 256]; }
    float s = v0 + v1, q = v0 * v0 + v1 * v1;
#pragma unroll
    for (int m = 1; m < 64; m <<= 1) { s += __shfl_xor(s, m); q += __shfl_xor(q, m); }
    __shared__ float ss[4], qq[4];
    int wid = tid >> 6;
    if ((tid & 63) == 0) { ss[wid] = s; qq[wid] = q; }
    __syncthreads();
    s = ss[0] + ss[1] + ss[2] + ss[3];
    q = qq[0] + qq[1] + qq[2] + qq[3];
    float mean = s * (1.f / C);
    float var = q * (1.f / C) - mean * mean;
    float rstd = rsqrtf(var + 1e-4f);
    float o0 = (v0 - mean) * rstd * g[tid] + be[tid];
    float o1 = (v1 - mean) * rstd * g[tid + 256] + be[tid + 256];
    xr[tid] = o0; xr[tid + 256] = o1;
    long b = bt >> 10, t = bt & (T - 1);
    bf16_t* xp = xpad + (b * (T + 2) + t + 1) * C;
    xp[tid] = (bf16_t)o0; xp[tid + 256] = (bf16_t)o1;
}

// ---------------- 128xBNT GEMM, BK=64, global_load_lds + XOR-swizzled LDS ----------------
// BNT=128: 4 waves in 2x2, acc[4][4].  BNT=64: 4 waves in 4x1 (32 M-rows each), acc[2][4].
// BNT=64 grids land on multiples of 256 blocks -> balanced CU load.
template <int OUTMODE, bool RELU, int NSPLIT, int IPT, int NTAPS, int BNT>
__global__ __launch_bounds__(256) void gemm128(
    const bf16_t* __restrict__ A, long batchStrideA, int lda,
    const bf16_t* __restrict__ Bw, long tapStrideB, int ldb,
    const float* __restrict__ bias0, const float* __restrict__ bias1,
    const float* __restrict__ bias2,
    void* __restrict__ Dp, void* __restrict__ D1p, void* __restrict__ D2p,
    long batchStrideD, int ldd) {
    __shared__ bf16_t As[128 * 64];
    __shared__ bf16_t Bs[BNT * 64];
    constexpr int WAVES_Y = (BNT == 128) ? 2 : 4;
    constexpr int WM = 128 / WAVES_Y;       // M-rows per wave: 64 or 32
    constexpr int MT = WM / 16;             // 4 or 2
    constexpr int CPW = BNT / 32;           // B chunks per wave: 4 or 2
    const int tid = threadIdx.x;
    const int lane = tid & 63, wid = tid >> 6;
    const int l15 = lane & 15, quad = lane >> 4;
    const int wy = (BNT == 128) ? (wid >> 1) : wid;
    const int wx = (BNT == 128) ? (wid & 1) : 0;
    const int nb = gridDim.z / NSPLIT;
    const int split = (NSPLIT > 1) ? ((int)blockIdx.z / nb) : 0;
    const int b = (int)blockIdx.z - split * nb;

    const bf16_t* Ab = A + (long)b * batchStrideA + (long)blockIdx.y * 128 * lda;
    const bf16_t* Bb = Bw + (long)blockIdx.x * BNT * ldb;

    const int lrow = lane >> 3;
    const int lcolsw = ((lane & 7) ^ lrow) * 8;

    f32x4 acc[MT][4];
#pragma unroll
    for (int i = 0; i < MT; ++i)
#pragma unroll
        for (int j = 0; j < 4; ++j) acc[i][j] = (f32x4){0.f, 0.f, 0.f, 0.f};

    constexpr int itersAll = IPT * NTAPS;
    constexpr int per = itersAll / NSPLIT;
    const int it0 = split * per;

    for (int it = it0; it < it0 + per; ++it) {
        const int tap = (NTAPS == 1) ? 0 : (it / IPT);
        const int k0 = (it - tap * IPT) * 64;
        const bf16_t* At = Ab + (long)tap * lda + k0;
        const bf16_t* Bt = Bb + (long)tap * tapStrideB + k0;
        __syncthreads();
#pragma unroll
        for (int i = 0; i < 4; ++i) {           // A: 16 chunks of 8 rows
            int chunk = wid * 4 + i;
            int row = chunk * 8 + lrow;
            gload_lds16(At + (long)row * lda + lcolsw, As + chunk * 512 + lane * 8);
        }
#pragma unroll
        for (int i = 0; i < CPW; ++i) {         // B: BNT/8 chunks
            int chunk = wid * CPW + i;
            int row = chunk * 8 + lrow;
            gload_lds16(Bt + (long)row * ldb + lcolsw, Bs + chunk * 512 + lane * 8);
        }
        __syncthreads();
#pragma unroll
        for (int ks = 0; ks < 2; ++ks) {
            bf16x8 bfr[4], afr[MT];
#pragma unroll
            for (int nt = 0; nt < 4; ++nt) {
                int row = wx * 64 + nt * 16 + l15;
                bfr[nt] = *(const bf16x8*)&Bs[row * 64 + (((ks * 4 + quad) ^ (l15 & 7)) * 8)];
            }
#pragma unroll
            for (int mt = 0; mt < MT; ++mt) {
                int row = wy * WM + mt * 16 + l15;
                afr[mt] = *(const bf16x8*)&As[row * 64 + (((ks * 4 + quad) ^ (l15 & 7)) * 8)];
            }
#pragma unroll
            for (int mt = 0; mt < MT; ++mt)
#pragma unroll
                for (int nt = 0; nt < 4; ++nt)
                    acc[mt][nt] = __builtin_amdgcn_mfma_f32_16x16x32_bf16(afr[mt], bfr[nt], acc[mt][nt], 0, 0, 0);
        }
    }

    const long m0 = (long)blockIdx.y * 128 + wy * WM;
    const int n0g = (int)blockIdx.x * BNT + wx * 64;
#pragma unroll
    for (int mt = 0; mt < MT; ++mt) {
        long rowb = m0 + mt * 16 + quad * 4;
#pragma unroll
        for (int nt = 0; nt < 4; ++nt) {
            int col = n0g + nt * 16 + l15;
            if (OUTMODE == 0) {
                float bb = (split == 0) ? bias0[col] : 0.f;
                float* D = ((split == 0) ? (float*)Dp : (split == 1) ? (float*)D1p : (float*)D2p)
                           + (long)b * batchStrideD;
#pragma unroll
                for (int r = 0; r < 4; ++r) D[(rowb + r) * ldd + col] = acc[mt][nt][r] + bb;
            } else if (OUTMODE == 1) {
                float bb = bias0[col];
                bf16_t* D = (bf16_t*)Dp + (long)b * batchStrideD;
#pragma unroll
                for (int r = 0; r < 4; ++r) {
                    float v = acc[mt][nt][r] + bb;
                    if (RELU) v = fmaxf(v, 0.f);
                    D[(rowb + r) * ldd + col] = (bf16_t)v;
                }
            } else {  // QKV fused
                int which = col >> 9, cl = col & 511;
                const float* bp = (which == 0) ? bias0 : (which == 1) ? bias1 : bias2;
                float bb = bp[cl];
                if (which < 2) {
                    bf16_t* D = (bf16_t*)((which == 0) ? Dp : D1p) + (long)b * T * C;
#pragma unroll
                    for (int r = 0; r < 4; ++r) D[(rowb + r) * C + cl] = (bf16_t)(acc[mt][nt][r] + bb);
                } else {
                    bf16_t* D = (bf16_t*)D2p + (long)b * C * T;
                    union { bf16_t h[4]; uint2 u; } pk;
#pragma unroll
                    for (int r = 0; r < 4; ++r) pk.h[r] = (bf16_t)(acc[mt][nt][r] + bb);
                    *(uint2*)(D + (long)cl * T + rowb) = pk.u;
                }
            }
        }
    }
}

// ---------------- fused attention: swapped-operand (S^T / O^T) flash kernel ----------------
// grid (T/64, H, B), 256 thr. Wave owns Q rows wid*16..+15. S^T = mfma(K,Q): lane holds 16
// scores of ONE Q row -> softmax = register tree + 2 shfls; O^T = mfma(V,P).
// ONE barrier per KV iteration: K(st+1), V(st+1) both staged one-ahead into the opposite
// dbuf slot; the barrier at the top of iter st+1 drains them (vmcnt(0) at s_barrier).
__global__ __launch_bounds__(256) void attn_kernel(const bf16_t* __restrict__ q,
                                                   const bf16_t* __restrict__ k,
                                                   const bf16_t* __restrict__ vT,
                                                   const float* __restrict__ relk,
                                                   bf16_t* __restrict__ y) {
    const int b = blockIdx.z, h = blockIdx.y;
    const int qt0 = blockIdx.x * 64;
    __shared__ bf16_t qps[64 * 72];      // swizzled Q [64][64] first, then P strips [8w][16][72]
    __shared__ bf16_t ktb[2][64 * 64];   // double-buffered swizzled K tiles
    __shared__ bf16_t vtb[2][64 * 64];   // double-buffered swizzled V^T tiles
    __shared__ float  rl[64][12];        // rel logits (exp2 domain)

    const int tid = threadIdx.x;
    const int lane = tid & 63, wid = tid >> 6;
    const int l15 = lane & 15, quad = lane >> 4;
    const int lrow = lane >> 3;                // 0..7 row within 8-row chunk
    const int su   = ((lane & 7) ^ lrow) * 8;  // swizzled source elem offset

    const bf16_t* qbase = q + ((size_t)(b * T + qt0)) * C + h * 64;
    const bf16_t* kbs = k + ((size_t)(b * T)) * C + h * 64;
    const bf16_t* vbs = vT + ((size_t)(b * C + h * 64)) * T;

    // prologue: stage Q + K/V tile 0, all async
#pragma unroll
    for (int i = 0; i < 2; ++i) {
        int chunk = wid * 2 + i;
        int row = chunk * 8 + lrow;
        gload_lds16(qbase + (long)row * C + su, qps + chunk * 512 + lane * 8);
        gload_lds16(kbs + (long)row * C + su, ktb[0] + chunk * 512 + lane * 8);
        gload_lds16(vbs + (long)row * T + su, vtb[0] + chunk * 512 + lane * 8);
    }
    __syncthreads();

    // rel logits: rl[r][j] = (SCALE*LOG2E) * q[r]·relk[j]   (reads swizzled qps)
    for (int i = tid; i < 64 * 9; i += 256) {
        int r = i / 9, j = i - r * 9;
        float acc = 0.f;
#pragma unroll
        for (int d = 0; d < 64; ++d)
            acc += (float)qps[r * 64 + ((d >> 3) ^ (r & 7)) * 8 + (d & 7)] * relk[j * 64 + d];
        rl[r][j] = acc * (SCALE * LOG2E);
    }
    __syncthreads();   // rl visible; all waves done reading qps as Q (P strips may overwrite)

    // Q fragments (B-operand role: col = q = l15 of wave's 16-row strip)
    const int qrow = wid * 16 + l15;
    bf16x8 af[2];
#pragma unroll
    for (int ks = 0; ks < 2; ++ks)
        af[ks] = *(const bf16x8*)&qps[qrow * 64 + (((ks * 4 + quad) ^ (qrow & 7)) * 8)];
    const float rl0 = rl[qrow][0], rl8 = rl[qrow][8];   // uniform-tile biases (register)

    float m_i = -1e30f, l_i = 0.f;   // lane-scalar online-softmax state (q = qrow)
    f32x4 o[4];
#pragma unroll
    for (int dn = 0; dn < 4; ++dn) o[dn] = (f32x4){0.f, 0.f, 0.f, 0.f};

    bf16_t* myP = qps + wid * (16 * 72);

    for (int st = 0; st < T / 64; ++st) {
        // single barrier: stage(st) complete (vmcnt drain), all waves done with buf[(st+1)&1]
        __syncthreads();
        if (st < T / 64 - 1) {
            const bf16_t* kb2 = kbs + (size_t)(st + 1) * 64 * C;
            const bf16_t* vb2 = vbs + (st + 1) * 64;
            bf16_t* kd = ktb[(st + 1) & 1];
            bf16_t* vd = vtb[(st + 1) & 1];
#pragma unroll
            for (int i = 0; i < 2; ++i) {
                int chunk = wid * 2 + i, row = chunk * 8 + lrow;
                gload_lds16(kb2 + (long)row * C + su, kd + chunk * 512 + lane * 8);
                gload_lds16(vb2 + (long)row * T + su, vd + chunk * 512 + lane * 8);
            }
        }
        const bf16_t* ktc = ktb[st & 1];
        const bf16_t* vtc = vtb[st & 1];

        // S^T tile: sc[nt][r] = S[s = nt*16 + quad*4 + r][q = l15]  (A=K, B=Q)
        f32x4 sc[4];
#pragma unroll
        for (int nt = 0; nt < 4; ++nt) {
            f32x4 a = (f32x4){0.f, 0.f, 0.f, 0.f};
#pragma unroll
            for (int ks = 0; ks < 2; ++ks) {
                int rr = nt * 16 + l15;
                bf16x8 kfr = *(const bf16x8*)&ktc[rr * 64 + (((ks * 4 + quad) ^ (l15 & 7)) * 8)];
                a = __builtin_amdgcn_mfma_f32_16x16x32_bf16(kfr, af[ks], a, 0, 0, 0);
            }
            sc[nt] = a;
        }

        // scale (exp2 domain) + rel bias.  d = s_g - q_g; j = clamp(d+4, 0, 8).
        const int base = st * 64 - qt0 - wid * 16;
        if (base >= 32) {
#pragma unroll
            for (int nt = 0; nt < 4; ++nt)
#pragma unroll
                for (int r = 0; r < 4; ++r) sc[nt][r] = sc[nt][r] * (SCALE * LOG2E) + rl8;
        } else if (base <= -80) {
#pragma unroll
            for (int nt = 0; nt < 4; ++nt)
#pragma unroll
                for (int r = 0; r < 4; ++r) sc[nt][r] = sc[nt][r] * (SCALE * LOG2E) + rl0;
        } else {
#pragma unroll
            for (int nt = 0; nt < 4; ++nt)
#pragma unroll
                for (int r = 0; r < 4; ++r) {
                    int j = base + nt * 16 + quad * 4 + r - l15 + 4;
                    j = j < 0 ? 0 : (j > 8 ? 8 : j);
                    sc[nt][r] = sc[nt][r] * (SCALE * LOG2E) + rl[qrow][j];
                }
        }

        // online softmax (base 2): 16 values in-lane + cross-quad combine (xor16, xor32)
        float mx = fmaxf(fmaxf(fmaxf(sc[0][0], sc[0][1]), fmaxf(sc[0][2], sc[0][3])),
                         fmaxf(fmaxf(sc[1][0], sc[1][1]), fmaxf(sc[1][2], sc[1][3])));
        mx = fmaxf(mx, fmaxf(fmaxf(fmaxf(sc[2][0], sc[2][1]), fmaxf(sc[2][2], sc[2][3])),
                             fmaxf(fmaxf(sc[3][0], sc[3][1]), fmaxf(sc[3][2], sc[3][3]))));
        mx = fmaxf(mx, __shfl_xor(mx, 16));
        mx = fmaxf(mx, __shfl_xor(mx, 32));
        float mn = fmaxf(m_i, mx);
        float alpha = exp2f(m_i - mn);
        m_i = mn;
        float rs = 0.f;
#pragma unroll
        for (int nt = 0; nt < 4; ++nt)
#pragma unroll
            for (int r = 0; r < 4; ++r) {
                float p = exp2f(sc[nt][r] - m_i);
                sc[nt][r] = p;
                rs += p;
            }
        rs += __shfl_xor(rs, 16);
        rs += __shfl_xor(rs, 32);
        l_i = l_i * alpha + rs;
#pragma unroll
        for (int dn = 0; dn < 4; ++dn) o[dn] *= alpha;

        // P strip: myP[q=l15][s] — wave-private, packed 4 x ds_write_b64 (no barrier needed)
#pragma unroll
        for (int nt = 0; nt < 4; ++nt) {
            union { bf16_t hh[4]; uint2 u; } pk;
#pragma unroll
            for (int r = 0; r < 4; ++r) pk.hh[r] = (bf16_t)sc[nt][r];
            *(uint2*)&myP[l15 * 72 + nt * 16 + quad * 4] = pk.u;
        }

        // O^T: o[dn] += mfma(A = V^T rows d, B = P^T cols q)  -> row = d, col = q = l15
        bf16x8 pb[2];
#pragma unroll
        for (int ks = 0; ks < 2; ++ks)
            pb[ks] = *(const bf16x8*)&myP[l15 * 72 + ks * 32 + quad * 8];
#pragma unroll
        for (int dn = 0; dn < 4; ++dn)
#pragma unroll
            for (int ks = 0; ks < 2; ++ks) {
                int rr = dn * 16 + l15;
                bf16x8 vf = *(const bf16x8*)&vtc[rr * 64 + (((ks * 4 + quad) ^ (l15 & 7)) * 8)];
                o[dn] = __builtin_amdgcn_mfma_f32_16x16x32_bf16(vf, pb[ks], o[dn], 0, 0, 0);
            }
    }

    // epilogue: lane (l15, quad) holds O^T[d = dn*16 + quad*4 + r][q = qrow]; write 8B packs
    float linv = 1.f / l_i;
    bf16_t* yb = y + ((size_t)(b * T + qt0 + qrow)) * C + h * 64;
#pragma unroll
    for (int dn = 0; dn < 4; ++dn) {
        union { bf16_t hh[4]; uint2 u; } pk;
#pragma unroll
        for (int r = 0; r < 4; ++r) pk.hh[r] = (bf16_t)(o[dn][r] * linv);
        *(uint2*)(yb + dn * 16 + quad * 4) = pk.u;
    }
}

// ---------------- host launch ----------------
extern "C" void kernel_launch(void* const* d_in, const int* in_sizes, int n_in,
                              void* d_out, int out_size, void* d_ws, size_t ws_size,
                              hipStream_t stream) {
    const float* x0  = (const float*)d_in[0];
    const float* wq  = (const float*)d_in[1];
    const float* bq  = (const float*)d_in[2];
    const float* wk  = (const float*)d_in[3];
    const float* bk  = (const float*)d_in[4];
    const float* wv  = (const float*)d_in[5];
    const float* bv  = (const float*)d_in[6];
    const float* wo  = (const float*)d_in[7];
    const float* bo  = (const float*)d_in[8];
    const float* rlk = (const float*)d_in[9];
    const float* g1  = (const float*)d_in[10];
    const float* be1 = (const float*)d_in[11];
    const float* w1  = (const float*)d_in[12];
    const float* bb1 = (const float*)d_in[13];
    const float* w2  = (const float*)d_in[14];
    const float* bb2 = (const float*)d_in[15];
    const float* g2  = (const float*)d_in[16];
    const float* be2 = (const float*)d_in[17];

    char* ws = (char*)d_ws;
    float*  xf    = (float*)(ws + OFF_XF);
    float*  yf    = (float*)(ws + OFF_YF);
    float*  yf2   = (float*)(ws + OFF_Q);       // aliases Q+K (dead at use time)
    float*  yf3   = (float*)(ws + OFF_VT);      // aliases VT+YA (dead during FFN2)
    bf16_t* xpad  = (bf16_t*)(ws + OFF_XPAD);
    bf16_t* qb    = (bf16_t*)(ws + OFF_Q);
    bf16_t* kb    = (bf16_t*)(ws + OFF_K);
    bf16_t* vTb   = (bf16_t*)(ws + OFF_VT);
    bf16_t* yab   = (bf16_t*)(ws + OFF_YA);
    bf16_t* midp  = (bf16_t*)(ws + OFF_MID);
    bf16_t* wslot0 = (bf16_t*)(ws + OFF_WQKVO);

    const bool hoist = ws_size >= WS_HOISTED;

    transpose_in<<<dim3(T / 32, C / 32, B), dim3(32, 8), 0, stream>>>(x0, xf, xpad);
    zero_pads<<<80, 256, 0, stream>>>(xpad, midp);

    if (hoist)   // convert all 6 layers' weights once, before the layer loop
        cvt_all<<<dim3(CVT_BLOCKS, L), 256, 0, stream>>>(wq, wk, wv, wo, w1, w2,
                                                         wslot0, 0, WSLOT_ELEM);

    for (int l = 0; l < L; ++l) {
        if (!hoist)
            cvt_all<<<dim3(CVT_BLOCKS, 1), 256, 0, stream>>>(wq, wk, wv, wo, w1, w2,
                                                             wslot0, l, 0);
        bf16_t* wbase = wslot0 + (hoist ? (size_t)l * WSLOT_ELEM : 0);
        bf16_t* wqkvo = wbase;
        bf16_t* w1b   = wbase + (size_t)4 * C * C;
        bf16_t* w2b   = wbase + (size_t)4 * C * C + (size_t)3 * FC * C;

        // fused QKV projection: N=1536, K=512 -> qb, kb, vT   (BN=64: 768 blocks = 3/CU)
        gemm128<3, false, 1, 8, 1, 64><<<dim3(1536 / 64, T / 128, B), 256, 0, stream>>>(
            xpad + C, (long)(T + 2) * C, C, wqkvo, 0, C,
            bq + l * C, bk + l * C, bv + l * C,
            (void*)qb, (void*)kb, (void*)vTb, 0, 0);

        attn_kernel<<<dim3(T / 64, H, B), 256, 0, stream>>>(qb, kb, vTb, rlk + (size_t)l * 9 * KC, yab);

        // O projection, split-K x2 -> f32 partials yf, yf2   (BN=64: 512 blocks = 2/CU)
        gemm128<0, false, 2, 8, 1, 64><<<dim3(C / 64, T / 128, 2 * B), 256, 0, stream>>>(
            yab, (long)T * C, C, wqkvo + 3 * C * C, 0, C,
            bo + l * C, nullptr, nullptr,
            (void*)yf, (void*)yf2, nullptr, (long)T * C, C);

        add_ln<2><<<B * T, 256, 0, stream>>>(xf, yf, yf2, nullptr, g1 + l * C, be1 + l * C, xpad);

        // FFN1: conv K=3 + bias + relu -> bf16 mid_pad rows 1..T   (BN=128: 512 blocks, balanced)
        gemm128<1, true, 1, 8, 3, 128><<<dim3(FC / 128, T / 128, B), 256, 0, stream>>>(
            xpad, (long)(T + 2) * C, C, w1b, (long)FC * C, C,
            bb1 + l * FC, nullptr, nullptr,
            (void*)(midp + FC), nullptr, nullptr, (long)(T + 2) * FC, FC);

        // FFN2: conv K=3, split-K x3 (tap-aligned) -> f32 partials   (BN=64: 768 blocks = 3/CU)
        gemm128<0, false, 3, 32, 3, 64><<<dim3(C / 64, T / 128, 3 * B), 256, 0, stream>>>(
            midp, (long)(T + 2) * FC, FC, w2b, (long)C * FC, FC,
            bb2 + l * C, nullptr, nullptr,
            (void*)yf, (void*)yf2, (void*)yf3, (long)T * C, C);

        add_ln<3><<<B * T, 256, 0, stream>>>(xf, yf, yf2, yf3, g2 + l * C, be2 + l * C, xpad);
    }

    transpose_out<<<dim3(T / 32, C / 32, B), dim3(32, 8), 0, stream>>>(xf, (float*)d_out);
}